// Round 5
// baseline (86.253 us; speedup 1.0000x reference)
//
#include <hip/hip_runtime.h>

// VQ-VAE quantizer: x[32][64][64][64] f32 NCHW, embed[1024][64] f32
// out: z_q (8388608 f32, NCHW) ++ loss (1 f32),  loss = 1.25*mean((z_q-z)^2)
//
// Block = 4 waves, 2 h-rows (128 positions); wave owns 32 positions (nt=2).
// Codebook streamed through LDS in 4 chunks of 256 codes (32 KB buffer; the
// z-tile stages into its first 16 KB and is consumed into B-frag registers
// before chunk 0 overwrites it). c0 (MFMA C-init) read from global (L1-hot)
// to keep the LDS pipe for A-frags. Grid 1024 -> 4 blocks/CU, 16 waves/CU.

#define TOTAL_ELEMS 8388608
#define LOSS_SCALE (1.25f / 8388608.f)

typedef float  f32x4  __attribute__((ext_vector_type(4)));
typedef __bf16 bf16x8 __attribute__((ext_vector_type(8)));
typedef unsigned int u32x4 __attribute__((ext_vector_type(4)));

static __device__ __forceinline__ unsigned short f2bf(float f) {
    unsigned int u = __float_as_uint(f);
    u += 0x7FFFu + ((u >> 16) & 1u);   // round-to-nearest-even
    return (unsigned short)(u >> 16);
}

// ---- prep: embed f32 -> bf16 copy + c0 = 0.25 - 0.5*||e||^2 + zero loss ----
__global__ void vq_prep(const float* __restrict__ embed,
                        unsigned short* __restrict__ eb,
                        float* __restrict__ c0,
                        float* __restrict__ loss_slot) {
    int t   = blockIdx.x * 256 + threadIdx.x;   // 0..4095
    int row = t >> 2, qd = t & 3;
    const float* src = embed + row * 64 + qd * 16;
    float s = 0.f;
    unsigned short tmp[16];
#pragma unroll
    for (int i = 0; i < 4; i++) {
        f32x4 v = *(const f32x4*)(src + i * 4);
#pragma unroll
        for (int j = 0; j < 4; j++) {
            float f = v[j];
            s += f * f;
            tmp[i * 4 + j] = f2bf(f);
        }
    }
    u32x4 w0, w1;
#pragma unroll
    for (int i = 0; i < 4; i++) {
        w0[i] = (unsigned)tmp[2*i]   | ((unsigned)tmp[2*i+1] << 16);
        w1[i] = (unsigned)tmp[8+2*i] | ((unsigned)tmp[8+2*i+1] << 16);
    }
    u32x4* dst = (u32x4*)(eb + row * 64 + qd * 16);
    dst[0] = w0; dst[1] = w1;
    s += __shfl_xor(s, 1);
    s += __shfl_xor(s, 2);
    if (qd == 0) c0[row] = 0.25f - 0.5f * s;    // MFMA C-init: acc = z.e + c0 > 0
    if (t == 0) *loss_slot = 0.f;
}

// argmin dist == argmax acc (acc = z.e + 0.25 - ||e||^2/2, strictly positive)
// key = (bits(acc) & ~1023) | (1023 - code)  -> pure u32 max chain
__global__ __launch_bounds__(256, 4) void vq_main(
    const float* __restrict__ x,
    const float* __restrict__ embed,            // f32, for exact gather
    const unsigned short* __restrict__ eb,      // bf16
    const float* __restrict__ c0,               // f32 per-code C-init (L1-hot)
    float* __restrict__ out,
    float* __restrict__ loss) {

    __shared__ __align__(16) unsigned char smem[32768]; // z-tile, then cb chunks
    __shared__ int   idxf[128];
    __shared__ float lpart[4];

    const int t    = threadIdx.x;
    const int wv   = t >> 6, lane = t & 63;
    const int l15  = lane & 15, lq = lane >> 4;
    const int c    = t & 63;                     // channel (staging/epilogue)
    const int g    = t >> 6;                     // quarter: hh = g>>1, w-half = g&1
    const int hh   = g >> 1, wh = g & 1;

    const int blk = blockIdx.x;                  // 0..1023 = 32 b x 32 h-pairs
    const int b   = blk >> 5;
    const int h0  = (blk & 31) * 2;
    const size_t xbase = (size_t)b * 262144 + (size_t)h0 * 64;

    // ---- issue codebook chunk 0 loads first (latency hides under z staging) ----
    u32x4 creg[8];
#pragma unroll
    for (int s = 0; s < 8; s++)
        creg[s] = *(const u32x4*)(eb + t * 64 + s * 8);

    // ---- stage z: 2 h-rows -> [pos][k] bf16, XOR-swizzled (first 16 KB) ----
#pragma unroll
    for (int i = 0; i < 8; i++) {
        int w0 = wh * 32 + i * 4;
        f32x4 v = *(const f32x4*)(x + xbase + (size_t)c * 4096 + (size_t)hh * 64 + w0);
#pragma unroll
        for (int j = 0; j < 4; j++) {
            int w = w0 + j;
            int byteoff = (hh * 64 + w) * 128 + ((c * 2) ^ ((w & 7) << 4));
            *(unsigned short*)(smem + byteoff) = f2bf(v[j]);
        }
    }
    __syncthreads();

    // ---- B-frags for this wave's 32 positions (8 VGPR, resident) ----
    bf16x8 bfr[2][2];
#pragma unroll
    for (int nt = 0; nt < 2; nt++) {
        int pos = wv * 32 + nt * 16 + l15;
        int rb  = pos * 128, sw = (pos & 7) << 4;
        bfr[nt][0] = *(const bf16x8*)(smem + rb + ((lq * 16) ^ sw));
        bfr[nt][1] = *(const bf16x8*)(smem + rb + ((64 + lq * 16) ^ sw));
    }
    __syncthreads();                             // z region dead -> reuse for cb

    // ---- write chunk 0 (thread t -> code row t, swizzled) ----
    {
        int rb = t * 128, sw = (t & 7) << 4;
#pragma unroll
        for (int s = 0; s < 8; s++)
            *(u32x4*)(smem + rb + ((s * 16) ^ sw)) = creg[s];
    }
    __syncthreads();

    // ---- 4 chunks x (16 mt x 2 nt x 2 MFMA) ----
    unsigned int key[2] = {0u, 0u};
#pragma unroll
    for (int ch = 0; ch < 4; ch++) {
        if (ch < 3) {                            // issue next chunk's loads early
#pragma unroll
            for (int s = 0; s < 8; s++)
                creg[s] = *(const u32x4*)(eb + (ch + 1) * 16384 + t * 64 + s * 8);
        }
        const int invc = 1023 - ch * 256 - lq * 4;
#pragma unroll
        for (int mt = 0; mt < 16; mt++) {
            int rb = (mt * 16 + l15) * 128, sw = (l15 & 7) << 4;
            bf16x8 a0 = *(const bf16x8*)(smem + rb + ((lq * 16) ^ sw));
            bf16x8 a1 = *(const bf16x8*)(smem + rb + ((64 + lq * 16) ^ sw));
            f32x4 c0v = *(const f32x4*)(c0 + ch * 256 + mt * 16 + lq * 4);  // L1-hot
            const int invm = invc - mt * 16;
#pragma unroll
            for (int nt = 0; nt < 2; nt++) {
                f32x4 acc = __builtin_amdgcn_mfma_f32_16x16x32_bf16(a0, bfr[nt][0], c0v, 0, 0, 0);
                acc = __builtin_amdgcn_mfma_f32_16x16x32_bf16(a1, bfr[nt][1], acc, 0, 0, 0);
                // D: col(l15)=pos-in-tile, row=(lq*4+r)=code-in-chunk
#pragma unroll
                for (int r = 0; r < 4; r++) {
                    unsigned int k2 = (__float_as_uint(acc[r]) & 0xFFFFFC00u)
                                    | (unsigned int)(invm - r);
                    key[nt] = key[nt] > k2 ? key[nt] : k2;
                }
            }
        }
        if (ch < 3) {
            __syncthreads();                     // all waves done reading chunk
            int rb = t * 128, sw = (t & 7) << 4;
#pragma unroll
            for (int s = 0; s < 8; s++)
                *(u32x4*)(smem + rb + ((s * 16) ^ sw)) = creg[s];
            __syncthreads();
        }
    }

    // ---- wave-local argmax reduce (codes spread over lane^16, lane^32) ----
#pragma unroll
    for (int nt = 0; nt < 2; nt++) {
        unsigned int k = key[nt];
        unsigned int o = (unsigned int)__shfl_xor((int)k, 16); k = k > o ? k : o;
        o = (unsigned int)__shfl_xor((int)k, 32);              k = k > o ? k : o;
        if (lane < 16) idxf[wv * 32 + nt * 16 + lane] = 1023 - (int)(k & 1023u);
    }
    __syncthreads();

    // ---- output: gather z_q (exact f32), write NCHW, loss partial ----
    float lsum = 0.f;
#pragma unroll
    for (int i = 0; i < 8; i++) {
        int w0 = wh * 32 + i * 4;
        const size_t off = xbase + (size_t)c * 4096 + (size_t)hh * 64 + w0;
        f32x4 xv = *(const f32x4*)(x + off);     // L1/L2-hot re-read
        f32x4 ov;
#pragma unroll
        for (int j = 0; j < 4; j++) {
            int idx = idxf[hh * 64 + w0 + j];    // uniform across wave
            float zq = embed[idx * 64 + c];      // coalesced 256B row read
            ov[j] = zq;
            float d = zq - xv[j];
            lsum += d * d;
        }
        *(f32x4*)(out + off) = ov;
    }

    // ---- block-reduce loss, one atomic per block ----
#pragma unroll
    for (int o2 = 1; o2 < 64; o2 <<= 1) lsum += __shfl_xor(lsum, o2);
    if (lane == 0) lpart[wv] = lsum;
    __syncthreads();
    if (t == 0)
        atomicAdd(loss, (lpart[0] + lpart[1] + lpart[2] + lpart[3]) * LOSS_SCALE);
}

extern "C" void kernel_launch(void* const* d_in, const int* in_sizes, int n_in,
                              void* d_out, int out_size, void* d_ws, size_t ws_size,
                              hipStream_t stream) {
    const float* x     = (const float*)d_in[0];
    const float* embed = (const float*)d_in[1];
    unsigned short* eb = (unsigned short*)d_ws;               // 1024*64 bf16 = 128 KB
    float* c0          = (float*)((char*)d_ws + 131072);      // 1024 f32  = 4 KB
    float* out  = (float*)d_out;
    float* loss = out + TOTAL_ELEMS;

    vq_prep<<<16, 256, 0, stream>>>(embed, eb, c0, loss);
    vq_main<<<1024, 256, 0, stream>>>(x, embed, eb, c0, out, loss);
}

// Round 6
// 49.639 us; speedup vs baseline: 1.7376x; 1.7376x over previous
//
#include <hip/hip_runtime.h>

// VQ-VAE quantizer: x[32][64][64][64] f32 NCHW, embed[1024][64] f32
// out: z_q (8388608 f32, NCHW) ++ loss (1 f32),  loss = 1.25*mean((z_q-z)^2)
//
// Block = 4 waves, 2 h-rows (128 positions); wave owns 32 positions (nt=2).
// Codebook streamed through LDS in 8 chunks of 128 codes, double-buffered,
// via global_load_lds DMA (zero VGPR staging -- R2/R3/R5 all spilled any
// register-staged codebook). eb is PRE-SWIZZLED by vq_prep so the linear DMA
// destination equals the XOR-swizzled layout the ds_reads expect.
// Loss computed from the winning keys: sum_ch(zq-z)^2 = ||z||^2 + 0.5 - 2*acc,
// so the epilogue never re-reads x.

#define TOTAL_ELEMS 8388608
#define LOSS_SCALE (1.25f / 8388608.f)

typedef float  f32x4  __attribute__((ext_vector_type(4)));
typedef __bf16 bf16x8 __attribute__((ext_vector_type(8)));
typedef unsigned int u32x4 __attribute__((ext_vector_type(4)));

static __device__ __forceinline__ unsigned short f2bf(float f) {
    unsigned int u = __float_as_uint(f);
    u += 0x7FFFu + ((u >> 16) & 1u);   // round-to-nearest-even
    return (unsigned short)(u >> 16);
}

static __device__ __forceinline__ void gload_lds16(const void* g, void* l) {
    __builtin_amdgcn_global_load_lds(
        (const __attribute__((address_space(1))) void*)g,
        (__attribute__((address_space(3))) void*)l,
        16, 0, 0);
}

// ---- prep: embed f32 -> bf16 PRE-SWIZZLED + c0 = 0.25 - 0.5*||e||^2 ----
__global__ void vq_prep(const float* __restrict__ embed,
                        unsigned short* __restrict__ eb,
                        float* __restrict__ c0,
                        float* __restrict__ loss_slot) {
    int t   = blockIdx.x * 256 + threadIdx.x;   // 0..4095
    int row = t >> 2, qd = t & 3;
    const float* src = embed + row * 64 + qd * 16;
    float s = 0.f;
    unsigned short tmp[16];
#pragma unroll
    for (int i = 0; i < 4; i++) {
        f32x4 v = *(const f32x4*)(src + i * 4);
#pragma unroll
        for (int j = 0; j < 4; j++) {
            float f = v[j];
            s += f * f;
            tmp[i * 4 + j] = f2bf(f);
        }
    }
    u32x4 w0, w1;
#pragma unroll
    for (int i = 0; i < 4; i++) {
        w0[i] = (unsigned)tmp[2*i]   | ((unsigned)tmp[2*i+1] << 16);
        w1[i] = (unsigned)tmp[8+2*i] | ((unsigned)tmp[8+2*i+1] << 16);
    }
    // swizzled store: element (row, byte k2) lives at row*128 + (k2 ^ ((row&7)<<4))
    char* dstb = (char*)eb + row * 128;
    const int sw = (row & 7) << 4;
    *(u32x4*)(dstb + ((qd * 32) ^ sw))      = w0;
    *(u32x4*)(dstb + ((qd * 32 + 16) ^ sw)) = w1;
    s += __shfl_xor(s, 1);
    s += __shfl_xor(s, 2);
    if (qd == 0) c0[row] = 0.25f - 0.5f * s;    // MFMA C-init: acc = z.e + c0 > 0
    if (t == 0) *loss_slot = 0.f;
}

// argmin dist == argmax acc (acc = z.e + 0.25 - ||e||^2/2, strictly positive)
// key = (bits(acc) & ~1023) | (1023 - code)  -> pure u32 max chain
__global__ __launch_bounds__(256, 4) void vq_main(
    const float* __restrict__ x,
    const float* __restrict__ embed,            // f32, for exact gather
    const unsigned short* __restrict__ eb,      // bf16, pre-swizzled rows
    const float* __restrict__ c0,               // f32 per-code C-init
    float* __restrict__ out,
    float* __restrict__ loss) {

    __shared__ __align__(16) unsigned char smem[2][16384];  // cb chunk dbuf / z-tile
    __shared__ __align__(16) float c0l[1024];
    __shared__ int   idxf[128];
    __shared__ float lpart[4];

    const int t    = threadIdx.x;
    const int wv   = t >> 6, lane = t & 63;
    const int l15  = lane & 15, lq = lane >> 4;

    const int blk = blockIdx.x;                  // 0..1023 = 32 b x 32 h-pairs
    const int b   = blk >> 5;
    const int h0  = (blk & 31) * 2;
    const size_t xbase = (size_t)b * 262144 + (size_t)h0 * 64;

    const char* ebp = (const char*)eb;

    // ---- chunk 0 DMA -> buf0 (async, no VGPRs) ----
#pragma unroll
    for (int s = 0; s < 4; s++)
        gload_lds16(ebp + (wv * 4 + s) * 1024 + lane * 16,
                    &smem[0][(wv * 4 + s) * 1024]);

    // ---- c0 -> LDS (4 KB, one b128 per thread) ----
    *(f32x4*)(c0l + t * 4) = *(const f32x4*)(c0 + t * 4);

    // ---- stage z -> buf1: thread = channels {2c2,2c2+1} x 16 w; z^2 partial ----
    const int c2 = t & 31, g = t >> 5;
    const int hh = g >> 2, w16 = (g & 3) * 16;
    float part = 0.f;
#pragma unroll
    for (int i = 0; i < 4; i++) {
        f32x4 v0 = *(const f32x4*)(x + xbase + (size_t)(2 * c2) * 4096 + hh * 64 + w16 + i * 4);
        f32x4 v1 = *(const f32x4*)(x + xbase + (size_t)(2 * c2 + 1) * 4096 + hh * 64 + w16 + i * 4);
#pragma unroll
        for (int j = 0; j < 4; j++) {
            int pos = hh * 64 + w16 + i * 4 + j;
            unsigned int val = (unsigned int)f2bf(v0[j]) | ((unsigned int)f2bf(v1[j]) << 16);
            part += v0[j] * v0[j] + v1[j] * v1[j];
            *(unsigned int*)(&smem[1][pos * 128 + ((c2 * 4) ^ ((pos & 7) << 4))]) = val;
        }
    }
    __syncthreads();                             // z + chunk0 DMA complete

    // ---- B-frags for this wave's 32 positions (16 VGPR, resident) ----
    bf16x8 bfr[2][2];
#pragma unroll
    for (int nt = 0; nt < 2; nt++) {
        int pos = wv * 32 + nt * 16 + l15;
        int rb  = pos * 128, sw = (pos & 7) << 4;
        bfr[nt][0] = *(const bf16x8*)(&smem[1][rb + ((lq * 16) ^ sw)]);
        bfr[nt][1] = *(const bf16x8*)(&smem[1][rb + ((64 + lq * 16) ^ sw)]);
    }
    __syncthreads();                             // buf1 dead -> DMA target

    // ---- 8 chunks x (8 mt x 2 nt x 2 MFMA), depth-1 DMA prefetch ----
    unsigned int key[2] = {0u, 0u};
#pragma unroll
    for (int ch = 0; ch < 8; ch++) {
        const int cur = ch & 1;
        if (ch < 7) {                            // DMA next chunk into other buf
#pragma unroll
            for (int s = 0; s < 4; s++)
                gload_lds16(ebp + (ch + 1) * 16384 + (wv * 4 + s) * 1024 + lane * 16,
                            &smem[cur ^ 1][(wv * 4 + s) * 1024]);
        }
        const int invc = 1023 - ch * 128 - lq * 4;
#pragma unroll
        for (int mt = 0; mt < 8; mt++) {
            int rb = (mt * 16 + l15) * 128, sw = (l15 & 7) << 4;
            bf16x8 a0 = *(const bf16x8*)(&smem[cur][rb + ((lq * 16) ^ sw)]);
            bf16x8 a1 = *(const bf16x8*)(&smem[cur][rb + ((64 + lq * 16) ^ sw)]);
            f32x4 c0v = *(const f32x4*)(c0l + ch * 128 + mt * 16 + lq * 4);  // broadcast
            const int invm = invc - mt * 16;
#pragma unroll
            for (int nt = 0; nt < 2; nt++) {
                f32x4 acc = __builtin_amdgcn_mfma_f32_16x16x32_bf16(a0, bfr[nt][0], c0v, 0, 0, 0);
                acc = __builtin_amdgcn_mfma_f32_16x16x32_bf16(a1, bfr[nt][1], acc, 0, 0, 0);
                // D: col(l15)=pos-in-tile, row=(lq*4+r)=code-in-16-tile
#pragma unroll
                for (int r = 0; r < 4; r++) {
                    unsigned int k2 = (__float_as_uint(acc[r]) & 0xFFFFFC00u)
                                    | (unsigned int)(invm - r);
                    key[nt] = key[nt] > k2 ? key[nt] : k2;
                }
            }
        }
        if (ch < 7) __syncthreads();             // drains DMA; guards buf reuse
    }

    // ---- wave-local argmax; loss contribution from keys ----
#pragma unroll
    for (int nt = 0; nt < 2; nt++) {
        unsigned int k = key[nt];
        unsigned int o = (unsigned int)__shfl_xor((int)k, 16); k = k > o ? k : o;
        o = (unsigned int)__shfl_xor((int)k, 32);              k = k > o ? k : o;
        // every lane now holds the final key for position (wv*32 + nt*16 + l15);
        // acc appears 4x per wave (lq replication): weight -2/4 = -0.5
        part -= 0.5f * __uint_as_float(k & 0xFFFFFC00u);
        if (lane < 16) idxf[wv * 32 + nt * 16 + lane] = 1023 - (int)(k & 1023u);
    }
#pragma unroll
    for (int o2 = 1; o2 < 64; o2 <<= 1) part += __shfl_xor(part, o2);
    if (lane == 0) lpart[wv] = part;
    __syncthreads();                             // idxf + lpart visible

    // ---- output: gather z_q (exact f32), write NCHW ----
    const int c = t & 63, g2 = t >> 6;
    const int eh = g2 >> 1, ew = (g2 & 1) * 32;
#pragma unroll
    for (int i = 0; i < 8; i++) {
        int w0 = ew + i * 4;
        const size_t off = xbase + (size_t)c * 4096 + eh * 64 + w0;
        f32x4 ov;
#pragma unroll
        for (int j = 0; j < 4; j++) {
            int idx = idxf[eh * 64 + w0 + j];     // wave-uniform
            ov[j] = embed[idx * 64 + c];          // coalesced 256B row read
        }
        *(f32x4*)(out + off) = ov;
    }

    // loss: sum_p dist_min = sum(z^2) + 0.5*128 - 2*sum(acc)
    if (t == 0)
        atomicAdd(loss, (lpart[0] + lpart[1] + lpart[2] + lpart[3] + 64.0f) * LOSS_SCALE);
}

extern "C" void kernel_launch(void* const* d_in, const int* in_sizes, int n_in,
                              void* d_out, int out_size, void* d_ws, size_t ws_size,
                              hipStream_t stream) {
    const float* x     = (const float*)d_in[0];
    const float* embed = (const float*)d_in[1];
    unsigned short* eb = (unsigned short*)d_ws;               // 1024*64 bf16 = 128 KB (swizzled)
    float* c0          = (float*)((char*)d_ws + 131072);      // 1024 f32  = 4 KB
    float* out  = (float*)d_out;
    float* loss = out + TOTAL_ELEMS;

    vq_prep<<<16, 256, 0, stream>>>(embed, eb, c0, loss);
    vq_main<<<1024, 256, 0, stream>>>(x, embed, eb, c0, out, loss);
}